// Round 4
// baseline (139.300 us; speedup 1.0000x reference)
//
#include <hip/hip_runtime.h>
#include <stdint.h>

typedef _Float16 half8  __attribute__((ext_vector_type(8)));
typedef float    f32x4  __attribute__((ext_vector_type(4)));
typedef uint32_t u32x4  __attribute__((ext_vector_type(4)));

#define NPIX 61504   // 16 * 62 * 62
#define LPB  3844    // 62*62
#define FIN  288
#define NOUT 64
#define KSPL 72
#define NXPIX 2097152        // 16*32*64*64
#define BFRAG_BYTES 332800   // 20736*16 rounded up to 256
#define BSP_BYTES   (NXPIX * 16)
#define WS_NEED     ((size_t)BFRAG_BYTES + (size_t)BSP_BYTES)

// ---------------- prep: weights -> f16 B-fragments in ws ----------------
// spline K-order: kt = ii*24 + jj*8 + g; quad q -> channel c = 4g+q;
// feature f = 9c + 3ii + jj. base part (kt>=72): natural feature order.
__global__ void prep_bfrag(const float* __restrict__ bw,
                           const float* __restrict__ sw,
                           const float* __restrict__ sc,
                           half8* __restrict__ bfrag) {
  int t = blockIdx.x * 256 + threadIdx.x;   // 0..20735
  half8 v;
  int dst;
  if (t < NOUT * FIN) {                     // spline (o,f) pairs
    int o = t / FIN;
    int f = t - o * FIN;
    float scale = sc[t];
    const float* p = sw + t * 8;
#pragma unroll
    for (int c = 0; c < 8; ++c) v[c] = (_Float16)(p[c] * scale);
    int ch = f / 9;
    int r  = f - ch * 9;
    int ii = r / 3;
    int jj = r - ii * 3;
    int g  = ch >> 2, q = ch & 3;
    int kt = ii * 24 + jj * 8 + g;
    dst = (kt * 4 + (o >> 4)) * 64 + q * 16 + (o & 15);
  } else {                                  // base frag-lanes
    int t2 = t - NOUT * FIN;
    int lane = t2 & 63;
    int nf = (t2 >> 6) & 3;
    int ktb = t2 >> 8;                      // 0..8
    int o = nf * 16 + (lane & 15);
    int f0 = ktb * 32 + (lane >> 4) * 8;
    const float* p = bw + o * FIN + f0;
#pragma unroll
    for (int c = 0; c < 8; ++c) v[c] = (_Float16)p[c];
    dst = ((KSPL + ktb) * 4 + nf) * 64 + lane;
  }
  bfrag[dst] = v;
}

// ---------------- cubic B-spline basis: 8 slots, f16-packed ----------------
__device__ inline half8 bspline8(float xv) {
  float u = fmaf(xv, 2.5f, 5.5f);
  float fi = floorf(u);
  int i = (int)fi;
  float t = u - fi, s = 1.0f - t;
  float t2 = t * t, t3 = t2 * t;
  float s2 = s * s, s3 = s2 * s;
  float w3 = t3 * 0.16666667f;
  float w0 = s3 * 0.16666667f;
  float w1 = fmaf(0.5f, t3, -t2) + 0.66666667f;
  float w2 = fmaf(0.5f, s3, -s2) + 0.66666667f;
  uint32_t u01 = __builtin_bit_cast(uint32_t, __builtin_amdgcn_cvt_pkrtz(w0, w1));
  uint32_t u23 = __builtin_bit_cast(uint32_t, __builtin_amdgcn_cvt_pkrtz(w2, w3));
  uint64_t V = (uint64_t)u01 | ((uint64_t)u23 << 32);
  uint32_t vl = (uint32_t)(V << 16);
  u32x4 fr;
#pragma unroll
  for (int q = 0; q < 4; ++q) {
    int d = i - 2 * q;
    uint32_t rr = (uint32_t)(V >> ((48 - 16 * d) & 63));
    fr[q] = ((uint32_t)d <= 3u) ? rr : ((d == 4) ? vl : 0u);
  }
  return __builtin_bit_cast(half8, fr);
}

// ---------------- precompute: basis per INPUT pixel (9x dedup) ----------------
__global__ void precompute_basis(const float* __restrict__ x,
                                 half8* __restrict__ bsp) {
  int i = blockIdx.x * 256 + threadIdx.x;   // 8192 blocks covers NXPIX exactly
  bsp[i] = bspline8(x[i]);
}

// ---------------- main v2: pure load + MFMA ----------------
// 961 blocks x 4 waves; wave = 16 px (wv*16 + m16) x 64 outs. No tail.
__global__ __launch_bounds__(256, 4) void kan_main2(
    const float* __restrict__ x,
    const half8* __restrict__ bsp,
    const half8* __restrict__ bfrag,
    float* __restrict__ out) {
  const int lane = threadIdx.x & 63;
  const int wv   = threadIdx.x >> 6;
  const int quad = lane >> 4;
  const int m16  = lane & 15;

  const int px = blockIdx.x * 64 + wv * 16 + m16;  // < 61504 exactly
  const int b  = px / LPB;
  const int l  = px - b * LPB;
  const int ho = l / 62;
  const int wo = l - ho * 62;
  const int xbase = b * 131072 + ho * 64 + wo;     // element idx ([b][c][h][w])

  f32x4 acc[4];
#pragma unroll
  for (int nf = 0; nf < 4; ++nf) acc[nf] = (f32x4){0.f, 0.f, 0.f, 0.f};

  const half8* abase = bsp + xbase + quad * 4096;  // channel = 4g + quad

  // ---- spline K: kt = ii*24 + jj*8 + g ----
  int kt = 0;
#pragma unroll
  for (int ii = 0; ii < 3; ++ii) {
#pragma unroll
    for (int jj = 0; jj < 3; ++jj) {
      const half8* ap = abase + ii * 64 + jj;
#pragma unroll
      for (int g = 0; g < 8; ++g) {
        half8 af = ap[g * 16384];                  // +4 channels per g
#pragma unroll
        for (int nf = 0; nf < 4; ++nf) {
          half8 bf = bfrag[(kt * 4 + nf) * 64 + lane];
          acc[nf] = __builtin_amdgcn_mfma_f32_16x16x32_f16(af, bf, acc[nf], 0, 0, 0);
        }
        ++kt;
      }
    }
  }

  // ---- base K: relu(x), natural feature order ----
#pragma unroll
  for (int kb = 0; kb < 9; ++kb) {
    int f0 = kb * 32 + quad * 8;
    half8 a;
#pragma unroll
    for (int j = 0; j < 8; ++j) {
      int f = f0 + j;
      int c = (f * 57) >> 9;            // f/9 (f<512)
      int r = f - c * 9;
      int i2 = (r * 11) >> 5;           // r/3 (r<9)
      int j2 = r - i2 * 3;
      a[j] = (_Float16)fmaxf(x[xbase + c * 4096 + i2 * 64 + j2], 0.0f);
    }
#pragma unroll
    for (int nf = 0; nf < 4; ++nf) {
      half8 bf = bfrag[((KSPL + kb) * 4 + nf) * 64 + lane];
      acc[nf] = __builtin_amdgcn_mfma_f32_16x16x32_f16(a, bf, acc[nf], 0, 0, 0);
    }
  }

  // ---- epilogue: col(out)=m16, row(pixel)=quad*4+rg ----
#pragma unroll
  for (int rg = 0; rg < 4; ++rg) {
    int p2 = blockIdx.x * 64 + wv * 16 + quad * 4 + rg;
    int b2 = p2 / LPB;
    int l2 = p2 - b2 * LPB;
    float* ob = out + b2 * (NOUT * LPB) + l2;
#pragma unroll
    for (int nf = 0; nf < 4; ++nf) {
      int o = nf * 16 + m16;
      ob[o * LPB] = acc[nf][rg];
    }
  }
}

// ================= fallback path (round-3, proven): used if ws too small ====
#define SC   200
#define LDSN (31*SC + 2*64 + 64 + 8)
__global__ __launch_bounds__(256, 4) void kan_main_fb(
    const float* __restrict__ x,
    const half8* __restrict__ bfrag,
    float* __restrict__ out) {
  __shared__ float lx[LDSN];
  const int tid = threadIdx.x;
  const int bid = blockIdx.x;
  const int b  = bid / 62;
  const int ho = bid - b * 62;
  const float* xb = x + b * 131072 + ho * 64;
#pragma unroll
  for (int r = 0; r < 6; ++r) {
    int gid = r * 256 + tid;
    int row = gid >> 4;
    int c   = (row * 683) >> 11;
    int ii  = row - c * 3;
    int colv = (gid & 15) * 4;
    const float4 v = *(const float4*)(xb + c * 4096 + ii * 64 + colv);
    *(float4*)(&lx[c * SC + ii * 64 + colv]) = v;
  }
  __syncthreads();
  const int lane = tid & 63;
  const int wv   = tid >> 6;
  const int quad = lane >> 4;
  const int m16  = lane & 15;
  const int wo   = wv * 16 + m16;
  f32x4 acc[4];
#pragma unroll
  for (int nf = 0; nf < 4; ++nf) acc[nf] = (f32x4){0.f, 0.f, 0.f, 0.f};
  int kt = 0;
#pragma unroll
  for (int ii = 0; ii < 3; ++ii) {
#pragma unroll
    for (int jj = 0; jj < 3; ++jj) {
      const float* lbase = lx + quad * SC + ii * 64 + wo + jj;
#pragma unroll
      for (int g = 0; g < 8; ++g) {
        float xv = lbase[g * (4 * SC)];
        half8 af = bspline8(xv);
#pragma unroll
        for (int nf = 0; nf < 4; ++nf) {
          half8 bf = bfrag[(kt * 4 + nf) * 64 + lane];
          acc[nf] = __builtin_amdgcn_mfma_f32_16x16x32_f16(af, bf, acc[nf], 0, 0, 0);
        }
        ++kt;
      }
    }
  }
#pragma unroll
  for (int kb = 0; kb < 9; ++kb) {
    int f0 = kb * 32 + quad * 8;
    half8 a;
#pragma unroll
    for (int j = 0; j < 8; ++j) {
      int f = f0 + j;
      int c = (f * 57) >> 9;
      int r = f - c * 9;
      int i2 = (r * 11) >> 5;
      int j2 = r - i2 * 3;
      a[j] = (_Float16)fmaxf(lx[c * SC + i2 * 64 + wo + j2], 0.0f);
    }
#pragma unroll
    for (int nf = 0; nf < 4; ++nf) {
      half8 bf = bfrag[((KSPL + kb) * 4 + nf) * 64 + lane];
      acc[nf] = __builtin_amdgcn_mfma_f32_16x16x32_f16(a, bf, acc[nf], 0, 0, 0);
    }
  }
  float* ob = out + b * (NOUT * LPB) + ho * 62;
#pragma unroll
  for (int rg = 0; rg < 4; ++rg) {
    int wo2 = wv * 16 + quad * 4 + rg;
    if (wo2 < 62) {
#pragma unroll
      for (int nf = 0; nf < 4; ++nf) {
        int o = nf * 16 + m16;
        ob[o * LPB + wo2] = acc[nf][rg];
      }
    }
  }
}

extern "C" void kernel_launch(void* const* d_in, const int* in_sizes, int n_in,
                              void* d_out, int out_size, void* d_ws, size_t ws_size,
                              hipStream_t stream) {
  const float* x  = (const float*)d_in[0];
  const float* bw = (const float*)d_in[1];  // (64, 288)
  const float* sw = (const float*)d_in[2];  // (64, 288, 8)
  const float* sc = (const float*)d_in[3];  // (64, 288)
  float* out = (float*)d_out;
  half8* bfrag = (half8*)d_ws;                              // 332,800 B
  half8* bsp   = (half8*)((char*)d_ws + BFRAG_BYTES);       // 33,554,432 B

  prep_bfrag<<<81, 256, 0, stream>>>(bw, sw, sc, bfrag);
  if (ws_size >= WS_NEED) {
    precompute_basis<<<NXPIX / 256, 256, 0, stream>>>(x, bsp);
    kan_main2<<<NPIX / 64, 256, 0, stream>>>(x, bsp, bfrag, out);
  } else {
    kan_main_fb<<<16 * 62, 256, 0, stream>>>(x, bfrag, out);
  }
}